// Round 8
// baseline (354.726 us; speedup 1.0000x reference)
//
#include <hip/hip_runtime.h>

// out0 = cumsum(z, axis=0), z fp32 [8192, 64, 128] -> 8192 rows x 8192 contiguous cols.
// out1 = previous_loss (1 float) at d_out[8192*8192].
//
// Fused single-kernel scan. Round 7 proved the phase-C z re-read hits the
// 256 MiB Infinity Cache (FETCH = 263 MB = ONE read of z) but ran 2 blocks/CU
// (latency-bound, 11% HBM). This round: 1024 blocks (4/CU, 16 waves/CU -- the
// occupancy that measured 86% HBM in rounds 1/3), KCH=128 x 8 tiles, R=64.
//   A: per-chunk aggregate (normal loads -> lines MALL-resident for C).
//   B: threads tid<chunk poll pred flags in parallel (<=127 preds, 2 waves),
//      then all 256 threads sum pred aggregates (L2/MALL traffic only).
//   C: re-read z (MALL-warm), running cumsum + prefix, nontemporal out stores
//      (no write-allocate -> doesn't evict z).
// All 1024 blocks co-resident (36 VGPR, 4 blocks/CU of 8 possible): the poll
// cannot deadlock regardless of dispatch order.

typedef float f4 __attribute__((ext_vector_type(4)));

constexpr int NROWS = 8192;
constexpr int NCOLS = 8192;
constexpr int NCOL4 = NCOLS / 4;     // 2048 float4 per row
constexpr int TPB   = 256;

constexpr int KCH   = 128;           // chunks (chain depth)
constexpr int R     = NROWS / KCH;   // 64 rows per chunk
constexpr int NTILE = NCOL4 / TPB;   // 8 column tiles
constexpr int GRID  = KCH * NTILE;   // 1024 blocks = 4/CU

__global__ __launch_bounds__(TPB) void k_onepass(
    const f4* __restrict__ z, f4* __restrict__ out,
    f4* __restrict__ agg, unsigned int* __restrict__ flags,
    const float* __restrict__ prev, float* __restrict__ out_tail)
{
    const int bid   = blockIdx.x;
    const int chunk = bid >> 3;          // chunk-major dispatch
    const int tile  = bid & (NTILE - 1);
    const int tid   = threadIdx.x;
    const int c4    = tile * TPB + tid;

    if (bid == 0 && tid == 0) out_tail[0] = prev[0];

    const f4* p = z + (size_t)chunk * R * NCOL4 + c4;

    // Phase A: chunk aggregate (normal loads -> lines cached for phase C).
    f4 a = (f4)0.f;
    #pragma unroll 16
    for (int r = 0; r < R; ++r) a += p[(size_t)r * NCOL4];

    const int slot = tile * KCH + chunk;          // per-chain contiguous
    agg[(size_t)slot * TPB + tid] = a;
    __threadfence();
    __syncthreads();
    if (tid == 0)
        __hip_atomic_store(&flags[slot], 1u, __ATOMIC_RELEASE,
                           __HIP_MEMORY_SCOPE_AGENT);

    // Phase B: threads tid<chunk poll predecessor flags in parallel, then all
    // threads sum predecessor aggregates (coalesced; agg is L2/MALL-resident).
    f4 prefix = (f4)0.f;
    if (chunk > 0) {
        if (tid < chunk) {   // chunk <= 127 -> first two waves poll
            const int fs = tile * KCH + tid;
            while (__hip_atomic_load(&flags[fs], __ATOMIC_RELAXED,
                                     __HIP_MEMORY_SCOPE_AGENT) == 0u)
                __builtin_amdgcn_s_sleep(8);
        }
        __syncthreads();
        __builtin_amdgcn_fence(__ATOMIC_ACQUIRE, "agent");
        const f4* ap = agg + (size_t)tile * KCH * TPB + tid;
        #pragma unroll 8
        for (int cp = 0; cp < chunk; ++cp)
            prefix += ap[(size_t)cp * TPB];
    }

    // Phase C: re-read z (MALL-warm), running cumsum, nontemporal out stores.
    f4* q = out + (size_t)chunk * R * NCOL4 + c4;
    f4 s = prefix;
    #pragma unroll 8
    for (int r = 0; r < R; ++r) {
        s += p[(size_t)r * NCOL4];
        __builtin_nontemporal_store(s, &q[(size_t)r * NCOL4]);
    }
}

// ---------- fallback 3-pass (known-good, 136 us) ----------
constexpr int FKCH = 128;
constexpr int FRR  = NROWS / FKCH;
constexpr int FCT  = NCOL4 / TPB;

__global__ __launch_bounds__(TPB) void k_partial(const f4* __restrict__ z,
                                                 f4* __restrict__ part) {
    const int tile  = blockIdx.x & (FCT - 1);
    const int chunk = blockIdx.x >> 3;
    const int c4    = tile * TPB + threadIdx.x;
    const f4* p = z + (size_t)chunk * FRR * NCOL4 + c4;
    f4 a = (f4)0.f;
    #pragma unroll 8
    for (int r = 0; r < FRR; ++r) a += p[(size_t)r * NCOL4];
    part[(size_t)chunk * NCOL4 + c4] = a;
}

__global__ __launch_bounds__(TPB) void k_scan(float* __restrict__ part,
                                              const float* __restrict__ prev,
                                              float* __restrict__ out_tail) {
    const int c = blockIdx.x * TPB + threadIdx.x;
    float run = 0.f;
    #pragma unroll 16
    for (int k = 0; k < FKCH; ++k) {
        const size_t i = (size_t)k * NCOLS + c;
        float v = part[i];
        part[i] = run;
        run += v;
    }
    if (blockIdx.x == 0 && threadIdx.x == 0) out_tail[0] = prev[0];
}

__global__ __launch_bounds__(TPB) void k_apply(const f4* __restrict__ z,
                                               const f4* __restrict__ part,
                                               f4* __restrict__ out) {
    const int tile  = blockIdx.x & (FCT - 1);
    const int chunk = FKCH - 1 - (blockIdx.x >> 3);
    const int c4    = tile * TPB + threadIdx.x;
    f4 a = part[(size_t)chunk * NCOL4 + c4];
    const f4* p = z   + (size_t)chunk * FRR * NCOL4 + c4;
    f4*       q = out + (size_t)chunk * FRR * NCOL4 + c4;
    #pragma unroll 4
    for (int r = 0; r < FRR; ++r) {
        a += p[(size_t)r * NCOL4];
        __builtin_nontemporal_store(a, &q[(size_t)r * NCOL4]);
    }
}

extern "C" void kernel_launch(void* const* d_in, const int* in_sizes, int n_in,
                              void* d_out, int out_size, void* d_ws, size_t ws_size,
                              hipStream_t stream) {
    const f4*    z    = (const f4*)d_in[0];
    const float* prev = (const float*)d_in[1];
    float*       out  = (float*)d_out;
    float*       tail = out + (size_t)NROWS * NCOLS;

    const size_t agg_bytes  = (size_t)GRID * TPB * sizeof(f4);  // 4 MiB
    const size_t flag_bytes = (size_t)GRID * sizeof(unsigned int);

    if (ws_size >= agg_bytes + flag_bytes) {
        f4* agg = (f4*)d_ws;
        unsigned int* flags = (unsigned int*)((char*)d_ws + agg_bytes);
        hipMemsetAsync(flags, 0, flag_bytes, stream);
        k_onepass<<<GRID, TPB, 0, stream>>>(z, (f4*)out, agg, flags, prev, tail);
    } else {
        float* part = (float*)d_ws;
        k_partial<<<FKCH * FCT, TPB, 0, stream>>>(z, (f4*)part);
        k_scan<<<NCOLS / TPB, TPB, 0, stream>>>(part, prev, tail);
        k_apply<<<FKCH * FCT, TPB, 0, stream>>>(z, (const f4*)part, (f4*)out);
    }
}

// Round 9
// 139.019 us; speedup vs baseline: 2.5516x; 2.5516x over previous
//
#include <hip/hip_runtime.h>

// out0 = cumsum(z, axis=0), z fp32 [8192, 64, 128] -> 8192 rows x 8192 contiguous cols.
// out1 = previous_loss (1 float) at d_out[8192*8192].
//
// Two-kernel streaming scan (rounds 5-8 established that every MALL-reuse
// scheme runs at ~1.3-2 TB/s effective -- slower than just re-reading z from
// HBM at ~6.9 TB/s -- so the 808 MB two-read structure is the right one):
//   k_partial: per-chunk per-column sums -> agg[128][8192] (4 MiB).
//   k_apply:   per-block prefix = sum of predecessor aggs (agg is L2-hot,
//              ~7 us chip-wide), then stream z -> out with nt stores.
// The kernel boundary guarantees agg visibility (no fences/flags); the
// separate latency-bound k_scan kernel and one launch gap are deleted.
// Summation grouping identical to round 3 (absmax 1.0).

typedef float f4 __attribute__((ext_vector_type(4)));

constexpr int NROWS = 8192;
constexpr int NCOLS = 8192;
constexpr int NCOL4 = NCOLS / 4;     // 2048 float4 per row
constexpr int TPB   = 256;
constexpr int KCH   = 128;           // row chunks
constexpr int RR    = NROWS / KCH;   // 64 rows per chunk
constexpr int CT    = NCOL4 / TPB;   // 8 column tiles -> 1024 blocks

// Pass 1: per-column sums of each row-chunk -> agg[KCH][NCOLS]; forward tail.
__global__ __launch_bounds__(TPB) void k_partial(const f4* __restrict__ z,
                                                 f4* __restrict__ agg,
                                                 const float* __restrict__ prev,
                                                 float* __restrict__ out_tail) {
    const int tile  = blockIdx.x & (CT - 1);
    const int chunk = blockIdx.x >> 3;
    const int c4    = tile * TPB + threadIdx.x;
    if (blockIdx.x == 0 && threadIdx.x == 0) out_tail[0] = prev[0];
    const f4* p = z + (size_t)chunk * RR * NCOL4 + c4;
    f4 a = (f4)0.f;
    #pragma unroll 8
    for (int r = 0; r < RR; ++r) a += p[(size_t)r * NCOL4];
    agg[(size_t)chunk * NCOL4 + c4] = a;
}

// Pass 2: prefix = sum of predecessor chunk aggregates (coalesced; agg is
// 4 MiB -> XCD-L2-resident after first touch), then re-read z, running cumsum,
// nontemporal out stores. Reversed chunk dispatch front-loads the deepest
// prefix sums.
__global__ __launch_bounds__(TPB) void k_apply(const f4* __restrict__ z,
                                               const f4* __restrict__ agg,
                                               f4* __restrict__ out) {
    const int tile  = blockIdx.x & (CT - 1);
    const int chunk = KCH - 1 - (blockIdx.x >> 3);
    const int c4    = tile * TPB + threadIdx.x;

    f4 s = (f4)0.f;
    const f4* ap = agg + c4;
    #pragma unroll 8
    for (int cp = 0; cp < chunk; ++cp) s += ap[(size_t)cp * NCOL4];

    const f4* p = z   + (size_t)chunk * RR * NCOL4 + c4;
    f4*       q = out + (size_t)chunk * RR * NCOL4 + c4;
    #pragma unroll 4
    for (int r = 0; r < RR; ++r) {
        s += p[(size_t)r * NCOL4];
        __builtin_nontemporal_store(s, &q[(size_t)r * NCOL4]);
    }
}

extern "C" void kernel_launch(void* const* d_in, const int* in_sizes, int n_in,
                              void* d_out, int out_size, void* d_ws, size_t ws_size,
                              hipStream_t stream) {
    const f4*    z    = (const f4*)d_in[0];
    const float* prev = (const float*)d_in[1];
    float*       out  = (float*)d_out;
    float*       tail = out + (size_t)NROWS * NCOLS;
    f4*          agg  = (f4*)d_ws;    // KCH*NCOL4 float4 = 4 MiB

    k_partial<<<KCH * CT, TPB, 0, stream>>>(z, agg, prev, tail);
    k_apply<<<KCH * CT, TPB, 0, stream>>>(z, (const f4*)agg, (f4*)out);
}